// Round 4
// baseline (2524.242 us; speedup 1.0000x reference)
//
#include <hip/hip_runtime.h>
#include <cstdint>
#include <cstddef>

#define N_NODES 50000
#define N_EDGES 400000
#define TOT_E   450000
#define G_GRAPHS 64
#define PB 256  // partial blocks for bnstats

// ---------------- graph build ----------------
__global__ void k_init_deg(int* __restrict__ deg) {
    int i = blockIdx.x * blockDim.x + threadIdx.x;
    if (i < N_NODES) deg[i] = 1;  // self loop
}

__global__ void k_hist(const int* __restrict__ ei, int* __restrict__ deg) {
    int e = blockIdx.x * blockDim.x + threadIdx.x;
    if (e < N_EDGES) atomicAdd(&deg[ei[N_EDGES + e]], 1);
}

__global__ void k_scan(const int* __restrict__ deg, int* __restrict__ rowptr,
                       int* __restrict__ cursor) {
    __shared__ int buf[1024];
    __shared__ int carry_s;
    int tid = threadIdx.x;
    if (tid == 0) carry_s = 0;
    __syncthreads();
    for (int base = 0; base < N_NODES; base += 1024) {
        int i = base + tid;
        int v = (i < N_NODES) ? deg[i] : 0;
        buf[tid] = v;
        __syncthreads();
        for (int off = 1; off < 1024; off <<= 1) {
            int t = (tid >= off) ? buf[tid - off] : 0;
            __syncthreads();
            buf[tid] += t;
            __syncthreads();
        }
        int excl = buf[tid] - v;
        int carry = carry_s;
        if (i < N_NODES) { rowptr[i] = carry + excl; cursor[i] = carry + excl; }
        __syncthreads();
        if (tid == 1023) carry_s += buf[1023];
        __syncthreads();
    }
    if (tid == 0) rowptr[N_NODES] = carry_s;
}

__global__ void k_scatter(const int* __restrict__ ei, int* __restrict__ cursor,
                          int* __restrict__ col, int* __restrict__ cdst) {
    int e = blockIdx.x * blockDim.x + threadIdx.x;
    if (e < N_EDGES) {
        int s = ei[e], d = ei[N_EDGES + e];
        int p = atomicAdd(&cursor[d], 1);
        col[p] = s;
        cdst[p] = d;
    } else if (e < TOT_E) {
        int i = e - N_EDGES;
        int p = atomicAdd(&cursor[i], 1);
        col[p] = i;
        cdst[p] = i;
    }
}

// ---------------- unified register-tiled GEMM ----------------
// Y[N,NO] = xform(X)[N,K] @ W[K,NO] (+ wb). CT<=64 cols/block, 64 rows/block.
// Inner loop: ds_read_b128 (wave-broadcast for CT=64) + 4 FMAs per read.
template<int K, int NO, bool XFORM, bool BIAS>
__global__ void k_mm(const float* __restrict__ X, const float* __restrict__ W,
                     const float* __restrict__ wb, const float* __restrict__ scale,
                     const float* __restrict__ shift, float* __restrict__ Y) {
    constexpr int CT = (NO < 64) ? NO : 64;   // columns per block
    constexpr int G  = 256 / CT;              // row groups
    constexpr int TM = 64;                    // rows per block
    constexpr int RT = TM / G;                // rows per thread
    constexpr int KB = (K < 32) ? K : 32;     // k chunk
    __shared__ float xs[TM][KB + 4];
    int c  = threadIdx.x % CT;
    int g  = threadIdx.x / CT;
    int r0 = blockIdx.x * TM;
    int c0 = blockIdx.y * CT;
    int myr = g * RT;
    float acc[RT];
#pragma unroll
    for (int r = 0; r < RT; r++) acc[r] = BIAS ? wb[c0 + c] : 0.f;

    for (int kb = 0; kb < K; kb += KB) {
        for (int i = threadIdx.x; i < TM * KB / 4; i += 256) {
            int rr = (i * 4) / KB, kk = (i * 4) % KB;
            float4 v = make_float4(0.f, 0.f, 0.f, 0.f);
            if (r0 + rr < N_NODES) {
                v = *(const float4*)&X[(size_t)(r0 + rr) * K + kb + kk];
                if (XFORM) {
                    v.x = fmaxf(v.x * scale[kb + kk] + shift[kb + kk], 0.f);
                    v.y = fmaxf(v.y * scale[kb + kk + 1] + shift[kb + kk + 1], 0.f);
                    v.z = fmaxf(v.z * scale[kb + kk + 2] + shift[kb + kk + 2], 0.f);
                    v.w = fmaxf(v.w * scale[kb + kk + 3] + shift[kb + kk + 3], 0.f);
                }
            }
            *(float4*)&xs[rr][kk] = v;
        }
        __syncthreads();
#pragma unroll
        for (int k = 0; k < KB; k += 4) {
            float w0 = W[(size_t)(kb + k) * NO + c0 + c];
            float w1 = W[(size_t)(kb + k + 1) * NO + c0 + c];
            float w2 = W[(size_t)(kb + k + 2) * NO + c0 + c];
            float w3 = W[(size_t)(kb + k + 3) * NO + c0 + c];
#pragma unroll
            for (int r = 0; r < RT; r++) {
                float4 xv = *(const float4*)&xs[myr + r][k];
                acc[r] = fmaf(xv.x, w0, fmaf(xv.y, w1, fmaf(xv.z, w2, fmaf(xv.w, w3, acc[r]))));
            }
        }
        __syncthreads();
    }
#pragma unroll
    for (int r = 0; r < RT; r++)
        if (r0 + myr + r < N_NODES) Y[(size_t)(r0 + myr + r) * NO + c0 + c] = acc[r];
}

// ---------------- attention scores (float4 vectorized) ----------------
template<int H, int C>
__global__ void k_scores(const float* __restrict__ Hm, const float* __restrict__ asrc,
                         const float* __restrict__ adst, float* __restrict__ ssrc,
                         float* __restrict__ sdst) {
    int t = blockIdx.x * blockDim.x + threadIdx.x;
    if (t >= N_NODES * H) return;
    int i = t / H, h = t - i * H;
    const float4* row = (const float4*)(Hm + (size_t)i * H * C + h * C);
    const float4* a1 = (const float4*)(asrc + h * C);
    const float4* a2 = (const float4*)(adst + h * C);
    float s1 = 0.f, s2 = 0.f;
#pragma unroll
    for (int c = 0; c < C / 4; c++) {
        float4 v = row[c];
        float4 x1 = a1[c], x2 = a2[c];
        s1 = fmaf(v.x, x1.x, fmaf(v.y, x1.y, fmaf(v.z, x1.z, fmaf(v.w, x1.w, s1))));
        s2 = fmaf(v.x, x2.x, fmaf(v.y, x2.y, fmaf(v.z, x2.z, fmaf(v.w, x2.w, s2))));
    }
    ssrc[t] = s1;
    sdst[t] = s2;
}

// ---------------- edge weights: w[p,h] = exp(leaky(ssrc[src]+sdst[dst])) ----------------
template<int H>
__global__ void k_ew(const float* __restrict__ ssrc, const float* __restrict__ sdst,
                     const int* __restrict__ col, const int* __restrict__ cdst,
                     float* __restrict__ w) {
    int t = blockIdx.x * blockDim.x + threadIdx.x;
    if (t >= TOT_E * H) return;
    int p = t / H, h = t - p * H;
    int s = col[p], d = cdst[p];
    float v = ssrc[(size_t)s * H + h] + sdst[(size_t)d * H + h];
    v = (v > 0.f) ? v : 0.2f * v;
    w[t] = __expf(v);
}

// ---------------- fused softmax-denominator + aggregation ----------------
template<int H, int C>
__global__ void k_agg(const float* __restrict__ Hm, const float* __restrict__ w,
                      const int* __restrict__ rowptr, const int* __restrict__ col,
                      const float* __restrict__ bias, float* __restrict__ out) {
    constexpr int HC = H * C;
    constexpr int K = HC / 64;
    int wid = (int)((blockIdx.x * blockDim.x + threadIdx.x) >> 6);
    int lane = threadIdx.x & 63;
    if (wid >= N_NODES) return;
    float acc[K];
    int hidx[K];
#pragma unroll
    for (int k = 0; k < K; k++) { acc[k] = 0.f; hidx[k] = (lane + 64 * k) / C; }
    float z = 0.f;
    int beg = rowptr[wid], end = rowptr[wid + 1];
    for (int base = beg; base < end; base += 64) {
        int nmax = min(64, end - base);
        int myc = (base + lane < end) ? col[base + lane] : 0;
        int j = 0;
        for (; j + 4 <= nmax; j += 4) {
            int s0 = __shfl(myc, j), s1 = __shfl(myc, j + 1);
            int s2 = __shfl(myc, j + 2), s3 = __shfl(myc, j + 3);
            float w0 = 0.f, w1 = 0.f, w2 = 0.f, w3 = 0.f;
            if (lane < H) {
                w0 = w[(size_t)(base + j) * H + lane];
                w1 = w[(size_t)(base + j + 1) * H + lane];
                w2 = w[(size_t)(base + j + 2) * H + lane];
                w3 = w[(size_t)(base + j + 3) * H + lane];
                z += (w0 + w1) + (w2 + w3);
            }
            const float* r0 = Hm + (size_t)s0 * HC;
            const float* r1 = Hm + (size_t)s1 * HC;
            const float* r2 = Hm + (size_t)s2 * HC;
            const float* r3 = Hm + (size_t)s3 * HC;
#pragma unroll
            for (int k = 0; k < K; k++) {
                int el = lane + 64 * k;
                float a0 = r0[el], a1 = r1[el], a2 = r2[el], a3 = r3[el];
                acc[k] = fmaf(__shfl(w0, hidx[k]), a0, acc[k]);
                acc[k] = fmaf(__shfl(w1, hidx[k]), a1, acc[k]);
                acc[k] = fmaf(__shfl(w2, hidx[k]), a2, acc[k]);
                acc[k] = fmaf(__shfl(w3, hidx[k]), a3, acc[k]);
            }
        }
        for (; j < nmax; j++) {
            int s0 = __shfl(myc, j);
            float w0 = 0.f;
            if (lane < H) { w0 = w[(size_t)(base + j) * H + lane]; z += w0; }
            const float* r0 = Hm + (size_t)s0 * HC;
#pragma unroll
            for (int k = 0; k < K; k++)
                acc[k] = fmaf(__shfl(w0, hidx[k]), r0[lane + 64 * k], acc[k]);
        }
    }
#pragma unroll
    for (int k = 0; k < K; k++) {
        float zk = __shfl(z, hidx[k]);
        int el = lane + 64 * k;
        out[(size_t)wid * HC + el] = acc[k] / (zk + 1e-16f) + bias[el];
    }
}

// ---------------- batchnorm stats: atomic-free per-block partials ----------------
template<int NO>
__global__ void k_bnstats(const float* __restrict__ X, float* __restrict__ psum,
                          float* __restrict__ psumsq) {
    constexpr int BS = (NO >= 256) ? NO : 256;
    constexpr int RPS = BS / NO;
    __shared__ float ls[BS], ls2[BS];
    int c = threadIdx.x % NO;
    int rsub = threadIdx.x / NO;
    constexpr int chunk = (N_NODES + PB - 1) / PB;
    int r0 = blockIdx.x * chunk;
    int r1 = min(N_NODES, r0 + chunk);
    float s = 0.f, s2 = 0.f;
    for (int r = r0 + rsub; r < r1; r += RPS) {
        float v = X[(size_t)r * NO + c];
        s += v;
        s2 += v * v;
    }
    if (RPS > 1) {
        ls[threadIdx.x] = s;
        ls2[threadIdx.x] = s2;
        __syncthreads();
        for (int off = BS / 2; off >= NO; off >>= 1) {
            if (threadIdx.x < off) {
                ls[threadIdx.x] += ls[threadIdx.x + off];
                ls2[threadIdx.x] += ls2[threadIdx.x + off];
            }
            __syncthreads();
        }
        s = ls[threadIdx.x];
        s2 = ls2[threadIdx.x];
    }
    if (rsub == 0) {
        psum[(size_t)blockIdx.x * NO + c] = s;
        psumsq[(size_t)blockIdx.x * NO + c] = s2;
    }
}

__global__ void k_bnfinal(const float* __restrict__ psum, const float* __restrict__ psumsq,
                          const float* __restrict__ g, const float* __restrict__ be,
                          float* __restrict__ scale, float* __restrict__ shift, int NO) {
    int t = threadIdx.x;
    if (t >= NO) return;
    float s = 0.f, s2 = 0.f;
    for (int b = 0; b < PB; b++) {
        s += psum[(size_t)b * NO + t];
        s2 += psumsq[(size_t)b * NO + t];
    }
    float mu = s / (float)N_NODES;
    float var = s2 / (float)N_NODES - mu * mu;
    float sc = g[t] * rsqrtf(var + 1e-5f);
    scale[t] = sc;
    shift[t] = be[t] - mu * sc;
}

// ---------------- pooling ----------------
__global__ void k_bhist(const int* __restrict__ batch, int* __restrict__ cnt) {
    __shared__ int h[G_GRAPHS];
    int tid = threadIdx.x;
    if (tid < G_GRAPHS) h[tid] = 0;
    __syncthreads();
    int i = blockIdx.x * blockDim.x + tid;
    if (i < N_NODES) atomicAdd(&h[batch[i]], 1);
    __syncthreads();
    if (tid < G_GRAPHS) atomicAdd(&cnt[tid], h[tid]);
}

__global__ void k_pool(const float* __restrict__ X, const int* __restrict__ batch,
                       const float* __restrict__ sc, const float* __restrict__ sh,
                       float* __restrict__ pooled) {
    int t = threadIdx.x;  // 384
    const int chunk = (N_NODES + 511) / 512;
    int r0 = blockIdx.x * chunk;
    int r1 = min(N_NODES, r0 + chunk);
    if (r0 >= N_NODES) return;
    float acc = 0.f;
    int cur = batch[r0];
    for (int r = r0; r < r1; r++) {
        int gid = batch[r];
        if (gid != cur) {
            atomicAdd(&pooled[(size_t)cur * 384 + t], acc);
            acc = 0.f;
            cur = gid;
        }
        float v = X[(size_t)r * 384 + t] * sc[t] + sh[t];
        acc += fmaxf(v, 0.f);
    }
    atomicAdd(&pooled[(size_t)cur * 384 + t], acc);
}

__global__ void k_final(const float* __restrict__ pooled, const int* __restrict__ cnt,
                        const float* __restrict__ lwf, const float* __restrict__ lbf,
                        float* __restrict__ out) {
    int t = threadIdx.x;  // 640
    if (t >= G_GRAPHS * 10) return;
    int g = t / 10, c = t - g * 10;
    float inv = 1.0f / fmaxf((float)cnt[g], 1.0f);
    float acc = lbf[c];
    for (int k = 0; k < 384; k++)
        acc = fmaf(pooled[(size_t)g * 384 + k] * inv, lwf[k * 10 + c], acc);
    out[t] = acc;
}

extern "C" void kernel_launch(void* const* d_in, const int* in_sizes, int n_in,
                              void* d_out, int out_size, void* d_ws, size_t ws_size,
                              hipStream_t stream) {
    const float* x    = (const float*)d_in[0];
    const int*   ei   = (const int*)d_in[1];
    const int*   batch= (const int*)d_in[2];
    const float* W1   = (const float*)d_in[3];
    const float* as1  = (const float*)d_in[4];
    const float* ad1  = (const float*)d_in[5];
    const float* b1   = (const float*)d_in[6];
    const float* g1   = (const float*)d_in[7];
    const float* be1  = (const float*)d_in[8];
    const float* lw1  = (const float*)d_in[9];
    const float* lb1  = (const float*)d_in[10];
    const float* gl1  = (const float*)d_in[11];
    const float* bel1 = (const float*)d_in[12];
    const float* W2   = (const float*)d_in[13];
    const float* as2  = (const float*)d_in[14];
    const float* ad2  = (const float*)d_in[15];
    const float* b2   = (const float*)d_in[16];
    const float* g2   = (const float*)d_in[17];
    const float* be2  = (const float*)d_in[18];
    const float* lw2  = (const float*)d_in[19];
    const float* lb2  = (const float*)d_in[20];
    const float* gl2  = (const float*)d_in[21];
    const float* bel2 = (const float*)d_in[22];
    const float* W3   = (const float*)d_in[23];
    const float* as3  = (const float*)d_in[24];
    const float* ad3  = (const float*)d_in[25];
    const float* b3   = (const float*)d_in[26];
    const float* g3   = (const float*)d_in[27];
    const float* be3  = (const float*)d_in[28];
    const float* lwf  = (const float*)d_in[29];
    const float* lbf  = (const float*)d_in[30];
    float* out = (float*)d_out;

    // ---- workspace carve ----
    char* p = (char*)d_ws;
    auto alloc = [&](size_t bytes) {
        char* r = p;
        p += (bytes + 255) & ~(size_t)255;
        return r;
    };
    int*   rowptr = (int*)alloc(4 * (size_t)(N_NODES + 1));
    int*   cursor = (int*)alloc(4 * (size_t)N_NODES);
    int*   deg    = (int*)alloc(4 * (size_t)N_NODES);
    int*   col    = (int*)alloc(4 * (size_t)TOT_E);
    int*   cdst   = (int*)alloc(4 * (size_t)TOT_E);
    float* ssrc   = (float*)alloc(4 * (size_t)N_NODES * 20);
    float* sdst   = (float*)alloc(4 * (size_t)N_NODES * 20);
    float* ew     = (float*)alloc(4 * (size_t)TOT_E * 20);
    float* hbuf   = (float*)alloc(4 * (size_t)N_NODES * 512);
    float* obuf   = (float*)alloc(4 * (size_t)N_NODES * 512);
    float* xbuf   = (float*)alloc(4 * (size_t)N_NODES * 32);
    float* psum   = (float*)alloc(4 * (size_t)PB * 512);
    float* psumsq = (float*)alloc(4 * (size_t)PB * 512);
    float* scA    = (float*)alloc(4 * 512);
    float* shA    = (float*)alloc(4 * 512);
    float* scB    = (float*)alloc(4 * 64);
    float* shB    = (float*)alloc(4 * 64);
    float* pooled = (float*)alloc(4 * (size_t)G_GRAPHS * 384);
    int*   cnt    = (int*)alloc(4 * G_GRAPHS);

    const int RB = (N_NODES + 63) / 64;  // 782 row-tiles

    // ---- graph build (reused by all 3 layers) ----
    k_init_deg<<<(N_NODES + 255) / 256, 256, 0, stream>>>(deg);
    k_hist<<<(N_EDGES + 255) / 256, 256, 0, stream>>>(ei, deg);
    k_scan<<<1, 1024, 0, stream>>>(deg, rowptr, cursor);
    k_scatter<<<(TOT_E + 255) / 256, 256, 0, stream>>>(ei, cursor, col, cdst);
    hipMemsetAsync(pooled, 0, 4 * (size_t)G_GRAPHS * 384 + 256, stream);  // pooled + cnt

    // ---- layer 1: GAT(128 -> 20x16) ----
    k_mm<128, 320, false, false><<<dim3(RB, 5), 256, 0, stream>>>(x, W1, nullptr, nullptr, nullptr, hbuf);
    k_scores<20, 16><<<(N_NODES * 20 + 255) / 256, 256, 0, stream>>>(hbuf, as1, ad1, ssrc, sdst);
    k_ew<20><<<(TOT_E * 20 + 255) / 256, 256, 0, stream>>>(ssrc, sdst, col, cdst, ew);
    k_agg<20, 16><<<(N_NODES + 3) / 4, 256, 0, stream>>>(hbuf, ew, rowptr, col, b1, obuf);
    k_bnstats<320><<<PB, 320, 0, stream>>>(obuf, psum, psumsq);
    k_bnfinal<<<1, 512, 0, stream>>>(psum, psumsq, g1, be1, scA, shA, 320);
    k_mm<320, 16, true, true><<<dim3(RB, 1), 256, 0, stream>>>(obuf, lw1, lb1, scA, shA, xbuf);
    k_bnstats<16><<<PB, 256, 0, stream>>>(xbuf, psum, psumsq);
    k_bnfinal<<<1, 512, 0, stream>>>(psum, psumsq, gl1, bel1, scB, shB, 16);

    // ---- layer 2: GAT(16 -> 16x32) ----
    k_mm<16, 512, true, false><<<dim3(RB, 8), 256, 0, stream>>>(xbuf, W2, nullptr, scB, shB, hbuf);
    k_scores<16, 32><<<(N_NODES * 16 + 255) / 256, 256, 0, stream>>>(hbuf, as2, ad2, ssrc, sdst);
    k_ew<16><<<(TOT_E * 16 + 255) / 256, 256, 0, stream>>>(ssrc, sdst, col, cdst, ew);
    k_agg<16, 32><<<(N_NODES + 3) / 4, 256, 0, stream>>>(hbuf, ew, rowptr, col, b2, obuf);
    k_bnstats<512><<<PB, 512, 0, stream>>>(obuf, psum, psumsq);
    k_bnfinal<<<1, 512, 0, stream>>>(psum, psumsq, g2, be2, scA, shA, 512);
    k_mm<512, 32, true, true><<<dim3(RB, 1), 256, 0, stream>>>(obuf, lw2, lb2, scA, shA, xbuf);
    k_bnstats<32><<<PB, 256, 0, stream>>>(xbuf, psum, psumsq);
    k_bnfinal<<<1, 512, 0, stream>>>(psum, psumsq, gl2, bel2, scB, shB, 32);

    // ---- layer 3: GAT(32 -> 8x48) ----
    k_mm<32, 384, true, false><<<dim3(RB, 6), 256, 0, stream>>>(xbuf, W3, nullptr, scB, shB, hbuf);
    k_scores<8, 48><<<(N_NODES * 8 + 255) / 256, 256, 0, stream>>>(hbuf, as3, ad3, ssrc, sdst);
    k_ew<8><<<(TOT_E * 8 + 255) / 256, 256, 0, stream>>>(ssrc, sdst, col, cdst, ew);
    k_agg<8, 48><<<(N_NODES + 3) / 4, 256, 0, stream>>>(hbuf, ew, rowptr, col, b3, obuf);
    k_bnstats<384><<<PB, 384, 0, stream>>>(obuf, psum, psumsq);
    k_bnfinal<<<1, 512, 0, stream>>>(psum, psumsq, g3, be3, scA, shA, 384);

    // ---- pool + classifier ----
    k_bhist<<<(N_NODES + 255) / 256, 256, 0, stream>>>(batch, cnt);
    k_pool<<<512, 384, 0, stream>>>(obuf, batch, scA, shA, pooled);
    k_final<<<1, 640, 0, stream>>>(pooled, cnt, lwf, lbf, out);
}

// Round 5
// 1646.665 us; speedup vs baseline: 1.5329x; 1.5329x over previous
//
#include <hip/hip_runtime.h>
#include <cstdint>
#include <cstddef>

#define N_NODES 50000
#define N_EDGES 400000
#define TOT_E   450000
#define G_GRAPHS 64
#define PB 256  // partial blocks for bnstats

// ---------------- graph build ----------------
__global__ void k_init_deg(int* __restrict__ deg) {
    int i = blockIdx.x * blockDim.x + threadIdx.x;
    if (i < N_NODES) deg[i] = 1;  // self loop
}

__global__ void k_hist(const int* __restrict__ ei, int* __restrict__ deg) {
    int e = blockIdx.x * blockDim.x + threadIdx.x;
    if (e < N_EDGES) atomicAdd(&deg[ei[N_EDGES + e]], 1);
}

__global__ void k_scan(const int* __restrict__ deg, int* __restrict__ rowptr,
                       int* __restrict__ cursor) {
    __shared__ int buf[1024];
    __shared__ int carry_s;
    int tid = threadIdx.x;
    if (tid == 0) carry_s = 0;
    __syncthreads();
    for (int base = 0; base < N_NODES; base += 1024) {
        int i = base + tid;
        int v = (i < N_NODES) ? deg[i] : 0;
        buf[tid] = v;
        __syncthreads();
        for (int off = 1; off < 1024; off <<= 1) {
            int t = (tid >= off) ? buf[tid - off] : 0;
            __syncthreads();
            buf[tid] += t;
            __syncthreads();
        }
        int excl = buf[tid] - v;
        int carry = carry_s;
        if (i < N_NODES) { rowptr[i] = carry + excl; cursor[i] = carry + excl; }
        __syncthreads();
        if (tid == 1023) carry_s += buf[1023];
        __syncthreads();
    }
    if (tid == 0) rowptr[N_NODES] = carry_s;
}

__global__ void k_scatter(const int* __restrict__ ei, int* __restrict__ cursor,
                          int* __restrict__ col, int* __restrict__ cdst) {
    int e = blockIdx.x * blockDim.x + threadIdx.x;
    if (e < N_EDGES) {
        int s = ei[e], d = ei[N_EDGES + e];
        int p = atomicAdd(&cursor[d], 1);
        col[p] = s;
        cdst[p] = d;
    } else if (e < TOT_E) {
        int i = e - N_EDGES;
        int p = atomicAdd(&cursor[i], 1);
        col[p] = i;
        cdst[p] = i;
    }
}

// ---------------- GEMM: Y[N,NO] = xform(X)[N,K] @ W[K,NO] ----------------
// Round-3 structure; inner loop upgraded to ds_read_b128 (4 FMAs per LDS read).
template<int K, int NO, bool XFORM>
__global__ void k_gemm(const float* __restrict__ X, const float* __restrict__ W,
                       const float* __restrict__ scale, const float* __restrict__ shift,
                       float* __restrict__ Y) {
    constexpr int R = 16;
    __shared__ float xs[R][K + 4];   // +4 keeps rows 16B-aligned
    int r0 = blockIdx.x * R;
    int tid = threadIdx.x;
    for (int i = tid; i < R * K / 4; i += NO) {
        int r = i / (K / 4), kq = (i % (K / 4)) * 4;
        float4 v = make_float4(0.f, 0.f, 0.f, 0.f);
        if (r0 + r < N_NODES) {
            v = *(const float4*)&X[(size_t)(r0 + r) * K + kq];
            if (XFORM) {
                v.x = fmaxf(v.x * scale[kq] + shift[kq], 0.f);
                v.y = fmaxf(v.y * scale[kq + 1] + shift[kq + 1], 0.f);
                v.z = fmaxf(v.z * scale[kq + 2] + shift[kq + 2], 0.f);
                v.w = fmaxf(v.w * scale[kq + 3] + shift[kq + 3], 0.f);
            }
        }
        *(float4*)&xs[r][kq] = v;
    }
    __syncthreads();
    int c = tid;  // < NO
    float acc[R];
#pragma unroll
    for (int r = 0; r < R; r++) acc[r] = 0.f;
#pragma unroll 4
    for (int k = 0; k < K; k += 4) {
        float w0 = W[(size_t)(k + 0) * NO + c];
        float w1 = W[(size_t)(k + 1) * NO + c];
        float w2 = W[(size_t)(k + 2) * NO + c];
        float w3 = W[(size_t)(k + 3) * NO + c];
#pragma unroll
        for (int r = 0; r < R; r++) {
            float4 xv = *(const float4*)&xs[r][k];
            acc[r] = fmaf(xv.x, w0, fmaf(xv.y, w1, fmaf(xv.z, w2, fmaf(xv.w, w3, acc[r]))));
        }
    }
#pragma unroll
    for (int r = 0; r < R; r++)
        if (r0 + r < N_NODES) Y[(size_t)(r0 + r) * NO + c] = acc[r];
}

// ---------------- attention scores (float4 vectorized) ----------------
template<int H, int C>
__global__ void k_scores(const float* __restrict__ Hm, const float* __restrict__ asrc,
                         const float* __restrict__ adst, float* __restrict__ ssrc,
                         float* __restrict__ sdst) {
    int t = blockIdx.x * blockDim.x + threadIdx.x;
    if (t >= N_NODES * H) return;
    int i = t / H, h = t - i * H;
    const float4* row = (const float4*)(Hm + (size_t)i * H * C + h * C);
    const float4* a1 = (const float4*)(asrc + h * C);
    const float4* a2 = (const float4*)(adst + h * C);
    float s1 = 0.f, s2 = 0.f;
#pragma unroll
    for (int c = 0; c < C / 4; c++) {
        float4 v = row[c];
        float4 x1 = a1[c], x2 = a2[c];
        s1 = fmaf(v.x, x1.x, fmaf(v.y, x1.y, fmaf(v.z, x1.z, fmaf(v.w, x1.w, s1))));
        s2 = fmaf(v.x, x2.x, fmaf(v.y, x2.y, fmaf(v.z, x2.z, fmaf(v.w, x2.w, s2))));
    }
    ssrc[t] = s1;
    sdst[t] = s2;
}

// ---------------- edge weights: w[p,h] = exp(leaky(ssrc[src]+sdst[dst])) ----------------
template<int H>
__global__ void k_ew(const float* __restrict__ ssrc, const float* __restrict__ sdst,
                     const int* __restrict__ col, const int* __restrict__ cdst,
                     float* __restrict__ w) {
    int t = blockIdx.x * blockDim.x + threadIdx.x;
    if (t >= TOT_E * H) return;
    int p = t / H, h = t - p * H;
    int s = col[p], d = cdst[p];
    float v = ssrc[(size_t)s * H + h] + sdst[(size_t)d * H + h];
    v = (v > 0.f) ? v : 0.2f * v;
    w[t] = __expf(v);
}

// ---------------- fused softmax-denominator + aggregation ----------------
template<int H, int C>
__global__ void k_agg(const float* __restrict__ Hm, const float* __restrict__ w,
                      const int* __restrict__ rowptr, const int* __restrict__ col,
                      const float* __restrict__ bias, float* __restrict__ out) {
    constexpr int HC = H * C;
    constexpr int K = HC / 64;
    int wid = (int)((blockIdx.x * blockDim.x + threadIdx.x) >> 6);
    int lane = threadIdx.x & 63;
    if (wid >= N_NODES) return;
    float acc[K];
    int hidx[K];
#pragma unroll
    for (int k = 0; k < K; k++) { acc[k] = 0.f; hidx[k] = (lane + 64 * k) / C; }
    float z = 0.f;
    int beg = rowptr[wid], end = rowptr[wid + 1];
    for (int base = beg; base < end; base += 64) {
        int nmax = min(64, end - base);
        int myc = (base + lane < end) ? col[base + lane] : 0;
        int j = 0;
        for (; j + 4 <= nmax; j += 4) {
            int s0 = __shfl(myc, j), s1 = __shfl(myc, j + 1);
            int s2 = __shfl(myc, j + 2), s3 = __shfl(myc, j + 3);
            float w0 = 0.f, w1 = 0.f, w2 = 0.f, w3 = 0.f;
            if (lane < H) {
                w0 = w[(size_t)(base + j) * H + lane];
                w1 = w[(size_t)(base + j + 1) * H + lane];
                w2 = w[(size_t)(base + j + 2) * H + lane];
                w3 = w[(size_t)(base + j + 3) * H + lane];
                z += (w0 + w1) + (w2 + w3);
            }
            const float* r0 = Hm + (size_t)s0 * HC;
            const float* r1 = Hm + (size_t)s1 * HC;
            const float* r2 = Hm + (size_t)s2 * HC;
            const float* r3 = Hm + (size_t)s3 * HC;
#pragma unroll
            for (int k = 0; k < K; k++) {
                int el = lane + 64 * k;
                float a0 = r0[el], a1 = r1[el], a2 = r2[el], a3 = r3[el];
                acc[k] = fmaf(__shfl(w0, hidx[k]), a0, acc[k]);
                acc[k] = fmaf(__shfl(w1, hidx[k]), a1, acc[k]);
                acc[k] = fmaf(__shfl(w2, hidx[k]), a2, acc[k]);
                acc[k] = fmaf(__shfl(w3, hidx[k]), a3, acc[k]);
            }
        }
        for (; j < nmax; j++) {
            int s0 = __shfl(myc, j);
            float w0 = 0.f;
            if (lane < H) { w0 = w[(size_t)(base + j) * H + lane]; z += w0; }
            const float* r0 = Hm + (size_t)s0 * HC;
#pragma unroll
            for (int k = 0; k < K; k++)
                acc[k] = fmaf(__shfl(w0, hidx[k]), r0[lane + 64 * k], acc[k]);
        }
    }
#pragma unroll
    for (int k = 0; k < K; k++) {
        float zk = __shfl(z, hidx[k]);
        int el = lane + 64 * k;
        out[(size_t)wid * HC + el] = acc[k] / (zk + 1e-16f) + bias[el];
    }
}

// ---------------- small linear: Y[N,NO] = relu(bn(X))[N,K] @ W[K,NO] + b ----------------
// Round-3 structure; inner loop upgraded to ds_read_b128.
template<int K, int NO>
__global__ void k_lin(const float* __restrict__ X, const float* __restrict__ W,
                      const float* __restrict__ wb, const float* __restrict__ scale,
                      const float* __restrict__ shift, float* __restrict__ Y) {
    constexpr int R = 256 / NO;
    __shared__ float xs[R][K + 4];   // +4 keeps rows 16B-aligned
    int r0 = blockIdx.x * R;
    int tid = threadIdx.x;
    for (int i = tid; i < R * K / 4; i += 256) {
        int r = i / (K / 4), kq = (i % (K / 4)) * 4;
        float4 v = make_float4(0.f, 0.f, 0.f, 0.f);
        if (r0 + r < N_NODES) {
            v = *(const float4*)&X[(size_t)(r0 + r) * K + kq];
            v.x = fmaxf(v.x * scale[kq] + shift[kq], 0.f);
            v.y = fmaxf(v.y * scale[kq + 1] + shift[kq + 1], 0.f);
            v.z = fmaxf(v.z * scale[kq + 2] + shift[kq + 2], 0.f);
            v.w = fmaxf(v.w * scale[kq + 3] + shift[kq + 3], 0.f);
        }
        *(float4*)&xs[r][kq] = v;
    }
    __syncthreads();
    int c = tid % NO, r = tid / NO;
    float acc = wb[c];
#pragma unroll 4
    for (int k = 0; k < K; k += 4) {
        float4 xv = *(const float4*)&xs[r][k];
        float w0 = W[(size_t)(k + 0) * NO + c];
        float w1 = W[(size_t)(k + 1) * NO + c];
        float w2 = W[(size_t)(k + 2) * NO + c];
        float w3 = W[(size_t)(k + 3) * NO + c];
        acc = fmaf(xv.x, w0, fmaf(xv.y, w1, fmaf(xv.z, w2, fmaf(xv.w, w3, acc))));
    }
    if (r0 + r < N_NODES) Y[(size_t)(r0 + r) * NO + c] = acc;
}

// ---------------- batchnorm stats: atomic-free per-block partials ----------------
template<int NO>
__global__ void k_bnstats(const float* __restrict__ X, float* __restrict__ psum,
                          float* __restrict__ psumsq) {
    constexpr int BS = (NO >= 256) ? NO : 256;
    constexpr int RPS = BS / NO;
    __shared__ float ls[BS], ls2[BS];
    int c = threadIdx.x % NO;
    int rsub = threadIdx.x / NO;
    constexpr int chunk = (N_NODES + PB - 1) / PB;
    int r0 = blockIdx.x * chunk;
    int r1 = min(N_NODES, r0 + chunk);
    float s = 0.f, s2 = 0.f;
    for (int r = r0 + rsub; r < r1; r += RPS) {
        float v = X[(size_t)r * NO + c];
        s += v;
        s2 += v * v;
    }
    if (RPS > 1) {
        ls[threadIdx.x] = s;
        ls2[threadIdx.x] = s2;
        __syncthreads();
        for (int off = BS / 2; off >= NO; off >>= 1) {
            if (threadIdx.x < off) {
                ls[threadIdx.x] += ls[threadIdx.x + off];
                ls2[threadIdx.x] += ls2[threadIdx.x + off];
            }
            __syncthreads();
        }
        s = ls[threadIdx.x];
        s2 = ls2[threadIdx.x];
    }
    if (rsub == 0) {
        psum[(size_t)blockIdx.x * NO + c] = s;
        psumsq[(size_t)blockIdx.x * NO + c] = s2;
    }
}

__global__ void k_bnfinal(const float* __restrict__ psum, const float* __restrict__ psumsq,
                          const float* __restrict__ g, const float* __restrict__ be,
                          float* __restrict__ scale, float* __restrict__ shift, int NO) {
    int t = threadIdx.x;
    if (t >= NO) return;
    float s = 0.f, s2 = 0.f;
    for (int b = 0; b < PB; b++) {
        s += psum[(size_t)b * NO + t];
        s2 += psumsq[(size_t)b * NO + t];
    }
    float mu = s / (float)N_NODES;
    float var = s2 / (float)N_NODES - mu * mu;
    float sc = g[t] * rsqrtf(var + 1e-5f);
    scale[t] = sc;
    shift[t] = be[t] - mu * sc;
}

// ---------------- pooling ----------------
__global__ void k_bhist(const int* __restrict__ batch, int* __restrict__ cnt) {
    __shared__ int h[G_GRAPHS];
    int tid = threadIdx.x;
    if (tid < G_GRAPHS) h[tid] = 0;
    __syncthreads();
    int i = blockIdx.x * blockDim.x + tid;
    if (i < N_NODES) atomicAdd(&h[batch[i]], 1);
    __syncthreads();
    if (tid < G_GRAPHS) atomicAdd(&cnt[tid], h[tid]);
}

__global__ void k_pool(const float* __restrict__ X, const int* __restrict__ batch,
                       const float* __restrict__ sc, const float* __restrict__ sh,
                       float* __restrict__ pooled) {
    int t = threadIdx.x;  // 384
    const int chunk = (N_NODES + 511) / 512;
    int r0 = blockIdx.x * chunk;
    int r1 = min(N_NODES, r0 + chunk);
    if (r0 >= N_NODES) return;
    float acc = 0.f;
    int cur = batch[r0];
    for (int r = r0; r < r1; r++) {
        int gid = batch[r];
        if (gid != cur) {
            atomicAdd(&pooled[(size_t)cur * 384 + t], acc);
            acc = 0.f;
            cur = gid;
        }
        float v = X[(size_t)r * 384 + t] * sc[t] + sh[t];
        acc += fmaxf(v, 0.f);
    }
    atomicAdd(&pooled[(size_t)cur * 384 + t], acc);
}

__global__ void k_final(const float* __restrict__ pooled, const int* __restrict__ cnt,
                        const float* __restrict__ lwf, const float* __restrict__ lbf,
                        float* __restrict__ out) {
    int t = threadIdx.x;  // 640
    if (t >= G_GRAPHS * 10) return;
    int g = t / 10, c = t - g * 10;
    float inv = 1.0f / fmaxf((float)cnt[g], 1.0f);
    float acc = lbf[c];
    for (int k = 0; k < 384; k++)
        acc = fmaf(pooled[(size_t)g * 384 + k] * inv, lwf[k * 10 + c], acc);
    out[t] = acc;
}

extern "C" void kernel_launch(void* const* d_in, const int* in_sizes, int n_in,
                              void* d_out, int out_size, void* d_ws, size_t ws_size,
                              hipStream_t stream) {
    const float* x    = (const float*)d_in[0];
    const int*   ei   = (const int*)d_in[1];
    const int*   batch= (const int*)d_in[2];
    const float* W1   = (const float*)d_in[3];
    const float* as1  = (const float*)d_in[4];
    const float* ad1  = (const float*)d_in[5];
    const float* b1   = (const float*)d_in[6];
    const float* g1   = (const float*)d_in[7];
    const float* be1  = (const float*)d_in[8];
    const float* lw1  = (const float*)d_in[9];
    const float* lb1  = (const float*)d_in[10];
    const float* gl1  = (const float*)d_in[11];
    const float* bel1 = (const float*)d_in[12];
    const float* W2   = (const float*)d_in[13];
    const float* as2  = (const float*)d_in[14];
    const float* ad2  = (const float*)d_in[15];
    const float* b2   = (const float*)d_in[16];
    const float* g2   = (const float*)d_in[17];
    const float* be2  = (const float*)d_in[18];
    const float* lw2  = (const float*)d_in[19];
    const float* lb2  = (const float*)d_in[20];
    const float* gl2  = (const float*)d_in[21];
    const float* bel2 = (const float*)d_in[22];
    const float* W3   = (const float*)d_in[23];
    const float* as3  = (const float*)d_in[24];
    const float* ad3  = (const float*)d_in[25];
    const float* b3   = (const float*)d_in[26];
    const float* g3   = (const float*)d_in[27];
    const float* be3  = (const float*)d_in[28];
    const float* lwf  = (const float*)d_in[29];
    const float* lbf  = (const float*)d_in[30];
    float* out = (float*)d_out;

    // ---- workspace carve ----
    char* p = (char*)d_ws;
    auto alloc = [&](size_t bytes) {
        char* r = p;
        p += (bytes + 255) & ~(size_t)255;
        return r;
    };
    int*   rowptr = (int*)alloc(4 * (size_t)(N_NODES + 1));
    int*   cursor = (int*)alloc(4 * (size_t)N_NODES);
    int*   deg    = (int*)alloc(4 * (size_t)N_NODES);
    int*   col    = (int*)alloc(4 * (size_t)TOT_E);
    int*   cdst   = (int*)alloc(4 * (size_t)TOT_E);
    float* ssrc   = (float*)alloc(4 * (size_t)N_NODES * 20);
    float* sdst   = (float*)alloc(4 * (size_t)N_NODES * 20);
    float* ew     = (float*)alloc(4 * (size_t)TOT_E * 20);
    float* hbuf   = (float*)alloc(4 * (size_t)N_NODES * 512);
    float* obuf   = (float*)alloc(4 * (size_t)N_NODES * 512);
    float* xbuf   = (float*)alloc(4 * (size_t)N_NODES * 32);
    float* psum   = (float*)alloc(4 * (size_t)PB * 512);
    float* psumsq = (float*)alloc(4 * (size_t)PB * 512);
    float* scA    = (float*)alloc(4 * 512);
    float* shA    = (float*)alloc(4 * 512);
    float* scB    = (float*)alloc(4 * 64);
    float* shB    = (float*)alloc(4 * 64);
    float* pooled = (float*)alloc(4 * (size_t)G_GRAPHS * 384);
    int*   cnt    = (int*)alloc(4 * G_GRAPHS);

    // ---- graph build (reused by all 3 layers) ----
    k_init_deg<<<(N_NODES + 255) / 256, 256, 0, stream>>>(deg);
    k_hist<<<(N_EDGES + 255) / 256, 256, 0, stream>>>(ei, deg);
    k_scan<<<1, 1024, 0, stream>>>(deg, rowptr, cursor);
    k_scatter<<<(TOT_E + 255) / 256, 256, 0, stream>>>(ei, cursor, col, cdst);
    hipMemsetAsync(pooled, 0, 4 * (size_t)G_GRAPHS * 384 + 256, stream);  // pooled + cnt

    // ---- layer 1: GAT(128 -> 20x16) ----
    k_gemm<128, 320, false><<<(N_NODES + 15) / 16, 320, 0, stream>>>(x, W1, nullptr, nullptr, hbuf);
    k_scores<20, 16><<<(N_NODES * 20 + 255) / 256, 256, 0, stream>>>(hbuf, as1, ad1, ssrc, sdst);
    k_ew<20><<<(TOT_E * 20 + 255) / 256, 256, 0, stream>>>(ssrc, sdst, col, cdst, ew);
    k_agg<20, 16><<<(N_NODES + 3) / 4, 256, 0, stream>>>(hbuf, ew, rowptr, col, b1, obuf);
    k_bnstats<320><<<PB, 320, 0, stream>>>(obuf, psum, psumsq);
    k_bnfinal<<<1, 512, 0, stream>>>(psum, psumsq, g1, be1, scA, shA, 320);
    k_lin<320, 16><<<(N_NODES + 15) / 16, 256, 0, stream>>>(obuf, lw1, lb1, scA, shA, xbuf);
    k_bnstats<16><<<PB, 256, 0, stream>>>(xbuf, psum, psumsq);
    k_bnfinal<<<1, 512, 0, stream>>>(psum, psumsq, gl1, bel1, scB, shB, 16);

    // ---- layer 2: GAT(16 -> 16x32) ----
    k_gemm<16, 512, true><<<(N_NODES + 15) / 16, 512, 0, stream>>>(xbuf, W2, scB, shB, hbuf);
    k_scores<16, 32><<<(N_NODES * 16 + 255) / 256, 256, 0, stream>>>(hbuf, as2, ad2, ssrc, sdst);
    k_ew<16><<<(TOT_E * 16 + 255) / 256, 256, 0, stream>>>(ssrc, sdst, col, cdst, ew);
    k_agg<16, 32><<<(N_NODES + 3) / 4, 256, 0, stream>>>(hbuf, ew, rowptr, col, b2, obuf);
    k_bnstats<512><<<PB, 512, 0, stream>>>(obuf, psum, psumsq);
    k_bnfinal<<<1, 512, 0, stream>>>(psum, psumsq, g2, be2, scA, shA, 512);
    k_lin<512, 32><<<(N_NODES + 7) / 8, 256, 0, stream>>>(obuf, lw2, lb2, scA, shA, xbuf);
    k_bnstats<32><<<PB, 256, 0, stream>>>(xbuf, psum, psumsq);
    k_bnfinal<<<1, 512, 0, stream>>>(psum, psumsq, gl2, bel2, scB, shB, 32);

    // ---- layer 3: GAT(32 -> 8x48) ----
    k_gemm<32, 384, true><<<(N_NODES + 15) / 16, 384, 0, stream>>>(xbuf, W3, scB, shB, hbuf);
    k_scores<8, 48><<<(N_NODES * 8 + 255) / 256, 256, 0, stream>>>(hbuf, as3, ad3, ssrc, sdst);
    k_ew<8><<<(TOT_E * 8 + 255) / 256, 256, 0, stream>>>(ssrc, sdst, col, cdst, ew);
    k_agg<8, 48><<<(N_NODES + 3) / 4, 256, 0, stream>>>(hbuf, ew, rowptr, col, b3, obuf);
    k_bnstats<384><<<PB, 384, 0, stream>>>(obuf, psum, psumsq);
    k_bnfinal<<<1, 512, 0, stream>>>(psum, psumsq, g3, be3, scA, shA, 384);

    // ---- pool + classifier ----
    k_bhist<<<(N_NODES + 255) / 256, 256, 0, stream>>>(batch, cnt);
    k_pool<<<512, 384, 0, stream>>>(obuf, batch, scA, shA, pooled);
    k_final<<<1, 640, 0, stream>>>(pooled, cnt, lwf, lbf, out);
}

// Round 6
// 1276.697 us; speedup vs baseline: 1.9772x; 1.2898x over previous
//
#include <hip/hip_runtime.h>
#include <cstdint>
#include <cstddef>

#define N_NODES 50000
#define N_EDGES 400000
#define TOT_E   450000
#define G_GRAPHS 64
#define PB 256  // partial blocks for bnstats

typedef unsigned short u16;
typedef unsigned int u32;

__device__ __forceinline__ float b2f(u16 v) {
    union { u32 u; float f; } x; x.u = ((u32)v) << 16; return x.f;
}
__device__ __forceinline__ float lo2f(u32 u) {
    union { u32 u; float f; } x; x.u = u << 16; return x.f;
}
__device__ __forceinline__ float hi2f(u32 u) {
    union { u32 u; float f; } x; x.u = u & 0xffff0000u; return x.f;
}
__device__ __forceinline__ u16 f2b(float f) {
    union { float f; u32 u; } x; x.f = f;
    u32 r = x.u + 0x7fffu + ((x.u >> 16) & 1u);  // round-nearest-even
    return (u16)(r >> 16);
}

// ---------------- graph build ----------------
__global__ void k_init_deg(int* __restrict__ deg) {
    int i = blockIdx.x * blockDim.x + threadIdx.x;
    if (i < N_NODES) deg[i] = 1;  // self loop
}

__global__ void k_hist(const int* __restrict__ ei, int* __restrict__ deg) {
    int e = blockIdx.x * blockDim.x + threadIdx.x;
    if (e < N_EDGES) atomicAdd(&deg[ei[N_EDGES + e]], 1);
}

__global__ void k_scan(const int* __restrict__ deg, int* __restrict__ rowptr,
                       int* __restrict__ cursor) {
    __shared__ int buf[1024];
    __shared__ int carry_s;
    int tid = threadIdx.x;
    if (tid == 0) carry_s = 0;
    __syncthreads();
    for (int base = 0; base < N_NODES; base += 1024) {
        int i = base + tid;
        int v = (i < N_NODES) ? deg[i] : 0;
        buf[tid] = v;
        __syncthreads();
        for (int off = 1; off < 1024; off <<= 1) {
            int t = (tid >= off) ? buf[tid - off] : 0;
            __syncthreads();
            buf[tid] += t;
            __syncthreads();
        }
        int excl = buf[tid] - v;
        int carry = carry_s;
        if (i < N_NODES) { rowptr[i] = carry + excl; cursor[i] = carry + excl; }
        __syncthreads();
        if (tid == 1023) carry_s += buf[1023];
        __syncthreads();
    }
    if (tid == 0) rowptr[N_NODES] = carry_s;
}

__global__ void k_scatter(const int* __restrict__ ei, int* __restrict__ cursor,
                          int* __restrict__ col, int* __restrict__ cdst) {
    int e = blockIdx.x * blockDim.x + threadIdx.x;
    if (e < N_EDGES) {
        int s = ei[e], d = ei[N_EDGES + e];
        int p = atomicAdd(&cursor[d], 1);
        col[p] = s;
        cdst[p] = d;
    } else if (e < TOT_E) {
        int i = e - N_EDGES;
        int p = atomicAdd(&cursor[i], 1);
        col[p] = i;
        cdst[p] = i;
    }
}

// ---------------- GEMM: Y[N,NO] = xform(X)[N,K] @ W[K,NO], bf16 output ----------------
// Round-3 structure (known-good); only the store converts to bf16.
template<int K, int NO, bool XFORM>
__global__ void k_gemm(const float* __restrict__ X, const float* __restrict__ W,
                       const float* __restrict__ scale, const float* __restrict__ shift,
                       u16* __restrict__ Y) {
    constexpr int R = 16;
    __shared__ float xs[R][K];
    int r0 = blockIdx.x * R;
    int tid = threadIdx.x;
    for (int idx = tid; idx < R * K; idx += NO) {
        int r = idx / K, k = idx - r * K;
        float v = 0.f;
        if (r0 + r < N_NODES) {
            v = X[(size_t)(r0 + r) * K + k];
            if (XFORM) { v = fmaxf(v * scale[k] + shift[k], 0.f); }
        }
        xs[r][k] = v;
    }
    __syncthreads();
    int c = tid;  // < NO
    float acc[R];
#pragma unroll
    for (int r = 0; r < R; r++) acc[r] = 0.f;
#pragma unroll 4
    for (int k = 0; k < K; k++) {
        float w = W[(size_t)k * NO + c];
#pragma unroll
        for (int r = 0; r < R; r++) acc[r] = fmaf(xs[r][k], w, acc[r]);
    }
#pragma unroll
    for (int r = 0; r < R; r++)
        if (r0 + r < N_NODES) Y[(size_t)(r0 + r) * NO + c] = f2b(acc[r]);
}

// ---------------- attention scores (bf16 input, uint-packed reads) ----------------
template<int H, int C>
__global__ void k_scores(const u16* __restrict__ Hm, const float* __restrict__ asrc,
                         const float* __restrict__ adst, float* __restrict__ ssrc,
                         float* __restrict__ sdst) {
    int t = blockIdx.x * blockDim.x + threadIdx.x;
    if (t >= N_NODES * H) return;
    int i = t / H, h = t - i * H;
    const u32* row = (const u32*)(Hm + (size_t)i * H * C + h * C);
    float s1 = 0.f, s2 = 0.f;
#pragma unroll
    for (int c2 = 0; c2 < C / 2; c2++) {
        u32 u = row[c2];
        float v0 = lo2f(u), v1 = hi2f(u);
        int c = c2 * 2;
        s1 = fmaf(v0, asrc[h * C + c], fmaf(v1, asrc[h * C + c + 1], s1));
        s2 = fmaf(v0, adst[h * C + c], fmaf(v1, adst[h * C + c + 1], s2));
    }
    ssrc[t] = s1;
    sdst[t] = s2;
}

// ---------------- edge weights: w[p,h] = exp(leaky(ssrc[src]+sdst[dst])) ----------------
template<int H>
__global__ void k_ew(const float* __restrict__ ssrc, const float* __restrict__ sdst,
                     const int* __restrict__ col, const int* __restrict__ cdst,
                     float* __restrict__ w) {
    int t = blockIdx.x * blockDim.x + threadIdx.x;
    if (t >= TOT_E * H) return;
    int p = t / H, h = t - p * H;
    int s = col[p], d = cdst[p];
    float v = ssrc[(size_t)s * H + h] + sdst[(size_t)d * H + h];
    v = (v > 0.f) ? v : 0.2f * v;
    w[t] = __expf(v);
}

// ---------------- fused softmax-denominator + aggregation (bf16 gather) ----------------
template<int H, int C>
__global__ void k_agg(const u16* __restrict__ Hm, const float* __restrict__ w,
                      const int* __restrict__ rowptr, const int* __restrict__ col,
                      const float* __restrict__ bias, float* __restrict__ out) {
    constexpr int HC = H * C;
    constexpr int K = HC / 64;
    int wid = (int)((blockIdx.x * blockDim.x + threadIdx.x) >> 6);
    int lane = threadIdx.x & 63;
    if (wid >= N_NODES) return;
    float acc[K];
    int hidx[K];
#pragma unroll
    for (int k = 0; k < K; k++) { acc[k] = 0.f; hidx[k] = (lane + 64 * k) / C; }
    float z = 0.f;
    int beg = rowptr[wid], end = rowptr[wid + 1];
    for (int base = beg; base < end; base += 64) {
        int nmax = min(64, end - base);
        int myc = (base + lane < end) ? col[base + lane] : 0;
        int j = 0;
        for (; j + 4 <= nmax; j += 4) {
            int s0 = __shfl(myc, j), s1 = __shfl(myc, j + 1);
            int s2 = __shfl(myc, j + 2), s3 = __shfl(myc, j + 3);
            float w0 = 0.f, w1 = 0.f, w2 = 0.f, w3 = 0.f;
            if (lane < H) {
                w0 = w[(size_t)(base + j) * H + lane];
                w1 = w[(size_t)(base + j + 1) * H + lane];
                w2 = w[(size_t)(base + j + 2) * H + lane];
                w3 = w[(size_t)(base + j + 3) * H + lane];
                z += (w0 + w1) + (w2 + w3);
            }
            const u16* r0 = Hm + (size_t)s0 * HC;
            const u16* r1 = Hm + (size_t)s1 * HC;
            const u16* r2 = Hm + (size_t)s2 * HC;
            const u16* r3 = Hm + (size_t)s3 * HC;
#pragma unroll
            for (int k = 0; k < K; k++) {
                int el = lane + 64 * k;
                float a0 = b2f(r0[el]), a1 = b2f(r1[el]);
                float a2 = b2f(r2[el]), a3 = b2f(r3[el]);
                acc[k] = fmaf(__shfl(w0, hidx[k]), a0, acc[k]);
                acc[k] = fmaf(__shfl(w1, hidx[k]), a1, acc[k]);
                acc[k] = fmaf(__shfl(w2, hidx[k]), a2, acc[k]);
                acc[k] = fmaf(__shfl(w3, hidx[k]), a3, acc[k]);
            }
        }
        for (; j < nmax; j++) {
            int s0 = __shfl(myc, j);
            float w0 = 0.f;
            if (lane < H) { w0 = w[(size_t)(base + j) * H + lane]; z += w0; }
            const u16* r0 = Hm + (size_t)s0 * HC;
#pragma unroll
            for (int k = 0; k < K; k++)
                acc[k] = fmaf(__shfl(w0, hidx[k]), b2f(r0[lane + 64 * k]), acc[k]);
        }
    }
#pragma unroll
    for (int k = 0; k < K; k++) {
        float zk = __shfl(z, hidx[k]);
        int el = lane + 64 * k;
        out[(size_t)wid * HC + el] = acc[k] / (zk + 1e-16f) + bias[el];
    }
}

// ---------------- small linear: Y[N,NO] = relu(bn(X))[N,K] @ W[K,NO] + b ----------------
// (round-3 exact code; input/output fp32)
template<int K, int NO>
__global__ void k_lin(const float* __restrict__ X, const float* __restrict__ W,
                      const float* __restrict__ wb, const float* __restrict__ scale,
                      const float* __restrict__ shift, float* __restrict__ Y) {
    constexpr int R = 256 / NO;
    __shared__ float xs[R][K + 1];
    int r0 = blockIdx.x * R;
    int tid = threadIdx.x;
    for (int idx = tid; idx < R * K; idx += 256) {
        int r = idx / K, k = idx - r * K;
        float v = 0.f;
        if (r0 + r < N_NODES) {
            v = X[(size_t)(r0 + r) * K + k];
            v = fmaxf(v * scale[k] + shift[k], 0.f);
        }
        xs[r][k] = v;
    }
    __syncthreads();
    int c = tid % NO, r = tid / NO;
    float acc = wb[c];
#pragma unroll 4
    for (int k = 0; k < K; k++) acc = fmaf(xs[r][k], W[(size_t)k * NO + c], acc);
    if (r0 + r < N_NODES) Y[(size_t)(r0 + r) * NO + c] = acc;
}

// ---------------- batchnorm stats: atomic-free per-block partials ----------------
template<int NO>
__global__ void k_bnstats(const float* __restrict__ X, float* __restrict__ psum,
                          float* __restrict__ psumsq) {
    constexpr int BS = (NO >= 256) ? NO : 256;
    constexpr int RPS = BS / NO;
    __shared__ float ls[BS], ls2[BS];
    int c = threadIdx.x % NO;
    int rsub = threadIdx.x / NO;
    constexpr int chunk = (N_NODES + PB - 1) / PB;
    int r0 = blockIdx.x * chunk;
    int r1 = min(N_NODES, r0 + chunk);
    float s = 0.f, s2 = 0.f;
    for (int r = r0 + rsub; r < r1; r += RPS) {
        float v = X[(size_t)r * NO + c];
        s += v;
        s2 += v * v;
    }
    if (RPS > 1) {
        ls[threadIdx.x] = s;
        ls2[threadIdx.x] = s2;
        __syncthreads();
        for (int off = BS / 2; off >= NO; off >>= 1) {
            if (threadIdx.x < off) {
                ls[threadIdx.x] += ls[threadIdx.x + off];
                ls2[threadIdx.x] += ls2[threadIdx.x + off];
            }
            __syncthreads();
        }
        s = ls[threadIdx.x];
        s2 = ls2[threadIdx.x];
    }
    if (rsub == 0) {
        psum[(size_t)blockIdx.x * NO + c] = s;
        psumsq[(size_t)blockIdx.x * NO + c] = s2;
    }
}

__global__ void k_bnfinal(const float* __restrict__ psum, const float* __restrict__ psumsq,
                          const float* __restrict__ g, const float* __restrict__ be,
                          float* __restrict__ scale, float* __restrict__ shift, int NO) {
    int t = threadIdx.x;
    if (t >= NO) return;
    float s = 0.f, s2 = 0.f;
    for (int b = 0; b < PB; b++) {
        s += psum[(size_t)b * NO + t];
        s2 += psumsq[(size_t)b * NO + t];
    }
    float mu = s / (float)N_NODES;
    float var = s2 / (float)N_NODES - mu * mu;
    float sc = g[t] * rsqrtf(var + 1e-5f);
    scale[t] = sc;
    shift[t] = be[t] - mu * sc;
}

// ---------------- pooling ----------------
__global__ void k_bhist(const int* __restrict__ batch, int* __restrict__ cnt) {
    __shared__ int h[G_GRAPHS];
    int tid = threadIdx.x;
    if (tid < G_GRAPHS) h[tid] = 0;
    __syncthreads();
    int i = blockIdx.x * blockDim.x + tid;
    if (i < N_NODES) atomicAdd(&h[batch[i]], 1);
    __syncthreads();
    if (tid < G_GRAPHS) atomicAdd(&cnt[tid], h[tid]);
}

__global__ void k_pool(const float* __restrict__ X, const int* __restrict__ batch,
                       const float* __restrict__ sc, const float* __restrict__ sh,
                       float* __restrict__ pooled) {
    int t = threadIdx.x;  // 384
    const int chunk = (N_NODES + 511) / 512;
    int r0 = blockIdx.x * chunk;
    int r1 = min(N_NODES, r0 + chunk);
    if (r0 >= N_NODES) return;
    float acc = 0.f;
    int cur = batch[r0];
    for (int r = r0; r < r1; r++) {
        int gid = batch[r];
        if (gid != cur) {
            atomicAdd(&pooled[(size_t)cur * 384 + t], acc);
            acc = 0.f;
            cur = gid;
        }
        float v = X[(size_t)r * 384 + t] * sc[t] + sh[t];
        acc += fmaxf(v, 0.f);
    }
    atomicAdd(&pooled[(size_t)cur * 384 + t], acc);
}

__global__ void k_final(const float* __restrict__ pooled, const int* __restrict__ cnt,
                        const float* __restrict__ lwf, const float* __restrict__ lbf,
                        float* __restrict__ out) {
    int t = threadIdx.x;  // 640
    if (t >= G_GRAPHS * 10) return;
    int g = t / 10, c = t - g * 10;
    float inv = 1.0f / fmaxf((float)cnt[g], 1.0f);
    float acc = lbf[c];
    for (int k = 0; k < 384; k++)
        acc = fmaf(pooled[(size_t)g * 384 + k] * inv, lwf[k * 10 + c], acc);
    out[t] = acc;
}

extern "C" void kernel_launch(void* const* d_in, const int* in_sizes, int n_in,
                              void* d_out, int out_size, void* d_ws, size_t ws_size,
                              hipStream_t stream) {
    const float* x    = (const float*)d_in[0];
    const int*   ei   = (const int*)d_in[1];
    const int*   batch= (const int*)d_in[2];
    const float* W1   = (const float*)d_in[3];
    const float* as1  = (const float*)d_in[4];
    const float* ad1  = (const float*)d_in[5];
    const float* b1   = (const float*)d_in[6];
    const float* g1   = (const float*)d_in[7];
    const float* be1  = (const float*)d_in[8];
    const float* lw1  = (const float*)d_in[9];
    const float* lb1  = (const float*)d_in[10];
    const float* gl1  = (const float*)d_in[11];
    const float* bel1 = (const float*)d_in[12];
    const float* W2   = (const float*)d_in[13];
    const float* as2  = (const float*)d_in[14];
    const float* ad2  = (const float*)d_in[15];
    const float* b2   = (const float*)d_in[16];
    const float* g2   = (const float*)d_in[17];
    const float* be2  = (const float*)d_in[18];
    const float* lw2  = (const float*)d_in[19];
    const float* lb2  = (const float*)d_in[20];
    const float* gl2  = (const float*)d_in[21];
    const float* bel2 = (const float*)d_in[22];
    const float* W3   = (const float*)d_in[23];
    const float* as3  = (const float*)d_in[24];
    const float* ad3  = (const float*)d_in[25];
    const float* b3   = (const float*)d_in[26];
    const float* g3   = (const float*)d_in[27];
    const float* be3  = (const float*)d_in[28];
    const float* lwf  = (const float*)d_in[29];
    const float* lbf  = (const float*)d_in[30];
    float* out = (float*)d_out;

    // ---- workspace carve ----
    char* p = (char*)d_ws;
    auto alloc = [&](size_t bytes) {
        char* r = p;
        p += (bytes + 255) & ~(size_t)255;
        return r;
    };
    int*   rowptr = (int*)alloc(4 * (size_t)(N_NODES + 1));
    int*   cursor = (int*)alloc(4 * (size_t)N_NODES);
    int*   deg    = (int*)alloc(4 * (size_t)N_NODES);
    int*   col    = (int*)alloc(4 * (size_t)TOT_E);
    int*   cdst   = (int*)alloc(4 * (size_t)TOT_E);
    float* ssrc   = (float*)alloc(4 * (size_t)N_NODES * 20);
    float* sdst   = (float*)alloc(4 * (size_t)N_NODES * 20);
    float* ew     = (float*)alloc(4 * (size_t)TOT_E * 20);
    u16*   hbuf   = (u16*)alloc(2 * (size_t)N_NODES * 512);
    float* obuf   = (float*)alloc(4 * (size_t)N_NODES * 512);
    float* xbuf   = (float*)alloc(4 * (size_t)N_NODES * 32);
    float* psum   = (float*)alloc(4 * (size_t)PB * 512);
    float* psumsq = (float*)alloc(4 * (size_t)PB * 512);
    float* scA    = (float*)alloc(4 * 512);
    float* shA    = (float*)alloc(4 * 512);
    float* scB    = (float*)alloc(4 * 64);
    float* shB    = (float*)alloc(4 * 64);
    float* pooled = (float*)alloc(4 * (size_t)G_GRAPHS * 384);
    int*   cnt    = (int*)alloc(4 * G_GRAPHS);

    // ---- graph build (reused by all 3 layers) ----
    k_init_deg<<<(N_NODES + 255) / 256, 256, 0, stream>>>(deg);
    k_hist<<<(N_EDGES + 255) / 256, 256, 0, stream>>>(ei, deg);
    k_scan<<<1, 1024, 0, stream>>>(deg, rowptr, cursor);
    k_scatter<<<(TOT_E + 255) / 256, 256, 0, stream>>>(ei, cursor, col, cdst);
    hipMemsetAsync(pooled, 0, 4 * (size_t)G_GRAPHS * 384 + 256, stream);  // pooled + cnt

    // ---- layer 1: GAT(128 -> 20x16) ----
    k_gemm<128, 320, false><<<(N_NODES + 15) / 16, 320, 0, stream>>>(x, W1, nullptr, nullptr, hbuf);
    k_scores<20, 16><<<(N_NODES * 20 + 255) / 256, 256, 0, stream>>>(hbuf, as1, ad1, ssrc, sdst);
    k_ew<20><<<(TOT_E * 20 + 255) / 256, 256, 0, stream>>>(ssrc, sdst, col, cdst, ew);
    k_agg<20, 16><<<(N_NODES + 3) / 4, 256, 0, stream>>>(hbuf, ew, rowptr, col, b1, obuf);
    k_bnstats<320><<<PB, 320, 0, stream>>>(obuf, psum, psumsq);
    k_bnfinal<<<1, 512, 0, stream>>>(psum, psumsq, g1, be1, scA, shA, 320);
    k_lin<320, 16><<<(N_NODES + 15) / 16, 256, 0, stream>>>(obuf, lw1, lb1, scA, shA, xbuf);
    k_bnstats<16><<<PB, 256, 0, stream>>>(xbuf, psum, psumsq);
    k_bnfinal<<<1, 512, 0, stream>>>(psum, psumsq, gl1, bel1, scB, shB, 16);

    // ---- layer 2: GAT(16 -> 16x32) ----
    k_gemm<16, 512, true><<<(N_NODES + 15) / 16, 512, 0, stream>>>(xbuf, W2, scB, shB, hbuf);
    k_scores<16, 32><<<(N_NODES * 16 + 255) / 256, 256, 0, stream>>>(hbuf, as2, ad2, ssrc, sdst);
    k_ew<16><<<(TOT_E * 16 + 255) / 256, 256, 0, stream>>>(ssrc, sdst, col, cdst, ew);
    k_agg<16, 32><<<(N_NODES + 3) / 4, 256, 0, stream>>>(hbuf, ew, rowptr, col, b2, obuf);
    k_bnstats<512><<<PB, 512, 0, stream>>>(obuf, psum, psumsq);
    k_bnfinal<<<1, 512, 0, stream>>>(psum, psumsq, g2, be2, scA, shA, 512);
    k_lin<512, 32><<<(N_NODES + 7) / 8, 256, 0, stream>>>(obuf, lw2, lb2, scA, shA, xbuf);
    k_bnstats<32><<<PB, 256, 0, stream>>>(xbuf, psum, psumsq);
    k_bnfinal<<<1, 512, 0, stream>>>(psum, psumsq, gl2, bel2, scB, shB, 32);

    // ---- layer 3: GAT(32 -> 8x48) ----
    k_gemm<32, 384, true><<<(N_NODES + 15) / 16, 384, 0, stream>>>(xbuf, W3, scB, shB, hbuf);
    k_scores<8, 48><<<(N_NODES * 8 + 255) / 256, 256, 0, stream>>>(hbuf, as3, ad3, ssrc, sdst);
    k_ew<8><<<(TOT_E * 8 + 255) / 256, 256, 0, stream>>>(ssrc, sdst, col, cdst, ew);
    k_agg<8, 48><<<(N_NODES + 3) / 4, 256, 0, stream>>>(hbuf, ew, rowptr, col, b3, obuf);
    k_bnstats<384><<<PB, 384, 0, stream>>>(obuf, psum, psumsq);
    k_bnfinal<<<1, 512, 0, stream>>>(psum, psumsq, g3, be3, scA, shA, 384);

    // ---- pool + classifier ----
    k_bhist<<<(N_NODES + 255) / 256, 256, 0, stream>>>(batch, cnt);
    k_pool<<<512, 384, 0, stream>>>(obuf, batch, scA, shA, pooled);
    k_final<<<1, 640, 0, stream>>>(pooled, cnt, lwf, lbf, out);
}

// Round 7
// 1168.372 us; speedup vs baseline: 2.1605x; 1.0927x over previous
//
#include <hip/hip_runtime.h>
#include <cstdint>
#include <cstddef>

#define N_NODES 50000
#define N_EDGES 400000
#define TOT_E   450000
#define G_GRAPHS 64
#define PB 256  // partial blocks for bnstats

typedef unsigned short u16;
typedef unsigned int u32;

__device__ __forceinline__ float b2f(u16 v) {
    union { u32 u; float f; } x; x.u = ((u32)v) << 16; return x.f;
}
__device__ __forceinline__ float lo2f(u32 u) {
    union { u32 u; float f; } x; x.u = u << 16; return x.f;
}
__device__ __forceinline__ float hi2f(u32 u) {
    union { u32 u; float f; } x; x.u = u & 0xffff0000u; return x.f;
}
__device__ __forceinline__ u16 f2b(float f) {
    union { float f; u32 u; } x; x.f = f;
    u32 r = x.u + 0x7fffu + ((x.u >> 16) & 1u);  // round-nearest-even
    return (u16)(r >> 16);
}

// ---------------- graph build ----------------
__global__ void k_init_deg(int* __restrict__ deg) {
    int i = blockIdx.x * blockDim.x + threadIdx.x;
    if (i < N_NODES) deg[i] = 1;  // self loop
}

__global__ void k_hist(const int* __restrict__ ei, int* __restrict__ deg) {
    int e = blockIdx.x * blockDim.x + threadIdx.x;
    if (e < N_EDGES) atomicAdd(&deg[ei[N_EDGES + e]], 1);
}

__global__ void k_scan(const int* __restrict__ deg, int* __restrict__ rowptr,
                       int* __restrict__ cursor) {
    __shared__ int buf[1024];
    __shared__ int carry_s;
    int tid = threadIdx.x;
    if (tid == 0) carry_s = 0;
    __syncthreads();
    for (int base = 0; base < N_NODES; base += 1024) {
        int i = base + tid;
        int v = (i < N_NODES) ? deg[i] : 0;
        buf[tid] = v;
        __syncthreads();
        for (int off = 1; off < 1024; off <<= 1) {
            int t = (tid >= off) ? buf[tid - off] : 0;
            __syncthreads();
            buf[tid] += t;
            __syncthreads();
        }
        int excl = buf[tid] - v;
        int carry = carry_s;
        if (i < N_NODES) { rowptr[i] = carry + excl; cursor[i] = carry + excl; }
        __syncthreads();
        if (tid == 1023) carry_s += buf[1023];
        __syncthreads();
    }
    if (tid == 0) rowptr[N_NODES] = carry_s;
}

__global__ void k_scatter(const int* __restrict__ ei, int* __restrict__ cursor,
                          int* __restrict__ col, int* __restrict__ cdst) {
    int e = blockIdx.x * blockDim.x + threadIdx.x;
    if (e < N_EDGES) {
        int s = ei[e], d = ei[N_EDGES + e];
        int p = atomicAdd(&cursor[d], 1);
        col[p] = s;
        cdst[p] = d;
    } else if (e < TOT_E) {
        int i = e - N_EDGES;
        int p = atomicAdd(&cursor[i], 1);
        col[p] = i;
        cdst[p] = i;
    }
}

// ---------------- GEMM: Y[N,NO] = xform(X)[N,K] @ W[K,NO], bf16 output ----------------
template<int K, int NO, bool XFORM>
__global__ void k_gemm(const float* __restrict__ X, const float* __restrict__ W,
                       const float* __restrict__ scale, const float* __restrict__ shift,
                       u16* __restrict__ Y) {
    constexpr int R = 16;
    __shared__ float xs[R][K];
    int r0 = blockIdx.x * R;
    int tid = threadIdx.x;
    for (int idx = tid; idx < R * K; idx += NO) {
        int r = idx / K, k = idx - r * K;
        float v = 0.f;
        if (r0 + r < N_NODES) {
            v = X[(size_t)(r0 + r) * K + k];
            if (XFORM) { v = fmaxf(v * scale[k] + shift[k], 0.f); }
        }
        xs[r][k] = v;
    }
    __syncthreads();
    int c = tid;  // < NO
    float acc[R];
#pragma unroll
    for (int r = 0; r < R; r++) acc[r] = 0.f;
#pragma unroll 4
    for (int k = 0; k < K; k++) {
        float w = W[(size_t)k * NO + c];
#pragma unroll
        for (int r = 0; r < R; r++) acc[r] = fmaf(xs[r][k], w, acc[r]);
    }
#pragma unroll
    for (int r = 0; r < R; r++)
        if (r0 + r < N_NODES) Y[(size_t)(r0 + r) * NO + c] = f2b(acc[r]);
}

// ---------------- attention scores (bf16 input, uint-packed reads) ----------------
template<int H, int C>
__global__ void k_scores(const u16* __restrict__ Hm, const float* __restrict__ asrc,
                         const float* __restrict__ adst, float* __restrict__ ssrc,
                         float* __restrict__ sdst) {
    int t = blockIdx.x * blockDim.x + threadIdx.x;
    if (t >= N_NODES * H) return;
    int i = t / H, h = t - i * H;
    const u32* row = (const u32*)(Hm + (size_t)i * H * C + h * C);
    float s1 = 0.f, s2 = 0.f;
#pragma unroll
    for (int c2 = 0; c2 < C / 2; c2++) {
        u32 u = row[c2];
        float v0 = lo2f(u), v1 = hi2f(u);
        int c = c2 * 2;
        s1 = fmaf(v0, asrc[h * C + c], fmaf(v1, asrc[h * C + c + 1], s1));
        s2 = fmaf(v0, adst[h * C + c], fmaf(v1, adst[h * C + c + 1], s2));
    }
    ssrc[t] = s1;
    sdst[t] = s2;
}

// ---------------- edge weights: w[p,h] = exp(leaky(ssrc[src]+sdst[dst])) ----------------
template<int H>
__global__ void k_ew(const float* __restrict__ ssrc, const float* __restrict__ sdst,
                     const int* __restrict__ col, const int* __restrict__ cdst,
                     float* __restrict__ w) {
    int t = blockIdx.x * blockDim.x + threadIdx.x;
    if (t >= TOT_E * H) return;
    int p = t / H, h = t - p * H;
    int s = col[p], d = cdst[p];
    float v = ssrc[(size_t)s * H + h] + sdst[(size_t)d * H + h];
    v = (v > 0.f) ? v : 0.2f * v;
    w[t] = __expf(v);
}

// ---------------- fused softmax-denominator + aggregation (bf16 gather) ----------------
template<int H, int C>
__global__ void k_agg(const u16* __restrict__ Hm, const float* __restrict__ w,
                      const int* __restrict__ rowptr, const int* __restrict__ col,
                      const float* __restrict__ bias, float* __restrict__ out) {
    constexpr int HC = H * C;
    constexpr int K = HC / 64;
    int wid = (int)((blockIdx.x * blockDim.x + threadIdx.x) >> 6);
    int lane = threadIdx.x & 63;
    if (wid >= N_NODES) return;
    float acc[K];
    int hidx[K];
#pragma unroll
    for (int k = 0; k < K; k++) { acc[k] = 0.f; hidx[k] = (lane + 64 * k) / C; }
    float z = 0.f;
    int beg = rowptr[wid], end = rowptr[wid + 1];
    for (int base = beg; base < end; base += 64) {
        int nmax = min(64, end - base);
        int myc = (base + lane < end) ? col[base + lane] : 0;
        int j = 0;
        for (; j + 4 <= nmax; j += 4) {
            int s0 = __shfl(myc, j), s1 = __shfl(myc, j + 1);
            int s2 = __shfl(myc, j + 2), s3 = __shfl(myc, j + 3);
            float w0 = 0.f, w1 = 0.f, w2 = 0.f, w3 = 0.f;
            if (lane < H) {
                w0 = w[(size_t)(base + j) * H + lane];
                w1 = w[(size_t)(base + j + 1) * H + lane];
                w2 = w[(size_t)(base + j + 2) * H + lane];
                w3 = w[(size_t)(base + j + 3) * H + lane];
                z += (w0 + w1) + (w2 + w3);
            }
            const u16* r0 = Hm + (size_t)s0 * HC;
            const u16* r1 = Hm + (size_t)s1 * HC;
            const u16* r2 = Hm + (size_t)s2 * HC;
            const u16* r3 = Hm + (size_t)s3 * HC;
#pragma unroll
            for (int k = 0; k < K; k++) {
                int el = lane + 64 * k;
                float a0 = b2f(r0[el]), a1 = b2f(r1[el]);
                float a2 = b2f(r2[el]), a3 = b2f(r3[el]);
                acc[k] = fmaf(__shfl(w0, hidx[k]), a0, acc[k]);
                acc[k] = fmaf(__shfl(w1, hidx[k]), a1, acc[k]);
                acc[k] = fmaf(__shfl(w2, hidx[k]), a2, acc[k]);
                acc[k] = fmaf(__shfl(w3, hidx[k]), a3, acc[k]);
            }
        }
        for (; j < nmax; j++) {
            int s0 = __shfl(myc, j);
            float w0 = 0.f;
            if (lane < H) { w0 = w[(size_t)(base + j) * H + lane]; z += w0; }
            const u16* r0 = Hm + (size_t)s0 * HC;
#pragma unroll
            for (int k = 0; k < K; k++)
                acc[k] = fmaf(__shfl(w0, hidx[k]), b2f(r0[lane + 64 * k]), acc[k]);
        }
    }
#pragma unroll
    for (int k = 0; k < K; k++) {
        float zk = __shfl(z, hidx[k]);
        int el = lane + 64 * k;
        out[(size_t)wid * HC + el] = acc[k] / (zk + 1e-16f) + bias[el];
    }
}

// ---------------- small linear: Y[N,NO] = relu(bn(X))[N,K] @ W[K,NO] + b ----------------
// Row-per-lane, all NO columns in registers. TPR waves split the K range;
// W/scale/shift indices are wave-uniform (readfirstlane) -> s_load + SGPR-FMA.
template<int K, int NO, int TPR>
__global__ void k_lin(const float* __restrict__ X, const float* __restrict__ W,
                      const float* __restrict__ wb, const float* __restrict__ scale,
                      const float* __restrict__ shift, float* __restrict__ Y) {
    constexpr int KS = K / TPR;  // k per wave-slice
    __shared__ float red[TPR][64][NO];
    int lane = threadIdx.x & 63;
    int wv = __builtin_amdgcn_readfirstlane(threadIdx.x >> 6);  // wave-uniform slice id
    int row = blockIdx.x * 64 + lane;
    int k0 = wv * KS;
    float acc[NO];
#pragma unroll
    for (int c = 0; c < NO; c++) acc[c] = 0.f;
    if (row < N_NODES) {
        const float* xr = X + (size_t)row * K + k0;
        for (int kk = 0; kk < KS; kk += 4) {
            float4 xv = *(const float4*)&xr[kk];
            int k = k0 + kk;
            float x0 = fmaxf(xv.x * scale[k] + shift[k], 0.f);
            float x1 = fmaxf(xv.y * scale[k + 1] + shift[k + 1], 0.f);
            float x2 = fmaxf(xv.z * scale[k + 2] + shift[k + 2], 0.f);
            float x3 = fmaxf(xv.w * scale[k + 3] + shift[k + 3], 0.f);
#pragma unroll
            for (int c = 0; c < NO; c++) {
                acc[c] = fmaf(x0, W[(size_t)k * NO + c],
                         fmaf(x1, W[(size_t)(k + 1) * NO + c],
                         fmaf(x2, W[(size_t)(k + 2) * NO + c],
                         fmaf(x3, W[(size_t)(k + 3) * NO + c], acc[c]))));
            }
        }
    }
#pragma unroll
    for (int c = 0; c < NO; c++) red[wv][lane][c] = acc[c];
    __syncthreads();
    // reduce TPR partials; coalesced store
    for (int i = threadIdx.x; i < 64 * NO; i += 64 * TPR) {
        int r = i / NO, c = i - r * NO;
        float s = wb[c];
#pragma unroll
        for (int t = 0; t < TPR; t++) s += red[t][r][c];
        int grow = blockIdx.x * 64 + r;
        if (grow < N_NODES) Y[(size_t)grow * NO + c] = s;
    }
}

// ---------------- batchnorm stats: atomic-free per-block partials ----------------
template<int NO>
__global__ void k_bnstats(const float* __restrict__ X, float* __restrict__ psum,
                          float* __restrict__ psumsq) {
    constexpr int BS = (NO >= 256) ? NO : 256;
    constexpr int RPS = BS / NO;
    __shared__ float ls[BS], ls2[BS];
    int c = threadIdx.x % NO;
    int rsub = threadIdx.x / NO;
    constexpr int chunk = (N_NODES + PB - 1) / PB;
    int r0 = blockIdx.x * chunk;
    int r1 = min(N_NODES, r0 + chunk);
    float s = 0.f, s2 = 0.f;
    for (int r = r0 + rsub; r < r1; r += RPS) {
        float v = X[(size_t)r * NO + c];
        s += v;
        s2 += v * v;
    }
    if (RPS > 1) {
        ls[threadIdx.x] = s;
        ls2[threadIdx.x] = s2;
        __syncthreads();
        for (int off = BS / 2; off >= NO; off >>= 1) {
            if (threadIdx.x < off) {
                ls[threadIdx.x] += ls[threadIdx.x + off];
                ls2[threadIdx.x] += ls2[threadIdx.x + off];
            }
            __syncthreads();
        }
        s = ls[threadIdx.x];
        s2 = ls2[threadIdx.x];
    }
    if (rsub == 0) {
        psum[(size_t)blockIdx.x * NO + c] = s;
        psumsq[(size_t)blockIdx.x * NO + c] = s2;
    }
}

__global__ void k_bnfinal(const float* __restrict__ psum, const float* __restrict__ psumsq,
                          const float* __restrict__ g, const float* __restrict__ be,
                          float* __restrict__ scale, float* __restrict__ shift, int NO) {
    int t = threadIdx.x;
    if (t >= NO) return;
    float s = 0.f, s2 = 0.f;
    for (int b = 0; b < PB; b++) {
        s += psum[(size_t)b * NO + t];
        s2 += psumsq[(size_t)b * NO + t];
    }
    float mu = s / (float)N_NODES;
    float var = s2 / (float)N_NODES - mu * mu;
    float sc = g[t] * rsqrtf(var + 1e-5f);
    scale[t] = sc;
    shift[t] = be[t] - mu * sc;
}

// ---------------- pooling ----------------
__global__ void k_bhist(const int* __restrict__ batch, int* __restrict__ cnt) {
    __shared__ int h[G_GRAPHS];
    int tid = threadIdx.x;
    if (tid < G_GRAPHS) h[tid] = 0;
    __syncthreads();
    int i = blockIdx.x * blockDim.x + tid;
    if (i < N_NODES) atomicAdd(&h[batch[i]], 1);
    __syncthreads();
    if (tid < G_GRAPHS) atomicAdd(&cnt[tid], h[tid]);
}

__global__ void k_pool(const float* __restrict__ X, const int* __restrict__ batch,
                       const float* __restrict__ sc, const float* __restrict__ sh,
                       float* __restrict__ pooled) {
    int t = threadIdx.x;  // 384
    const int chunk = (N_NODES + 511) / 512;
    int r0 = blockIdx.x * chunk;
    int r1 = min(N_NODES, r0 + chunk);
    if (r0 >= N_NODES) return;
    float acc = 0.f;
    int cur = batch[r0];
    for (int r = r0; r < r1; r++) {
        int gid = batch[r];
        if (gid != cur) {
            atomicAdd(&pooled[(size_t)cur * 384 + t], acc);
            acc = 0.f;
            cur = gid;
        }
        float v = X[(size_t)r * 384 + t] * sc[t] + sh[t];
        acc += fmaxf(v, 0.f);
    }
    atomicAdd(&pooled[(size_t)cur * 384 + t], acc);
}

__global__ void k_final(const float* __restrict__ pooled, const int* __restrict__ cnt,
                        const float* __restrict__ lwf, const float* __restrict__ lbf,
                        float* __restrict__ out) {
    int t = threadIdx.x;  // 640
    if (t >= G_GRAPHS * 10) return;
    int g = t / 10, c = t - g * 10;
    float inv = 1.0f / fmaxf((float)cnt[g], 1.0f);
    float acc = lbf[c];
    for (int k = 0; k < 384; k++)
        acc = fmaf(pooled[(size_t)g * 384 + k] * inv, lwf[k * 10 + c], acc);
    out[t] = acc;
}

extern "C" void kernel_launch(void* const* d_in, const int* in_sizes, int n_in,
                              void* d_out, int out_size, void* d_ws, size_t ws_size,
                              hipStream_t stream) {
    const float* x    = (const float*)d_in[0];
    const int*   ei   = (const int*)d_in[1];
    const int*   batch= (const int*)d_in[2];
    const float* W1   = (const float*)d_in[3];
    const float* as1  = (const float*)d_in[4];
    const float* ad1  = (const float*)d_in[5];
    const float* b1   = (const float*)d_in[6];
    const float* g1   = (const float*)d_in[7];
    const float* be1  = (const float*)d_in[8];
    const float* lw1  = (const float*)d_in[9];
    const float* lb1  = (const float*)d_in[10];
    const float* gl1  = (const float*)d_in[11];
    const float* bel1 = (const float*)d_in[12];
    const float* W2   = (const float*)d_in[13];
    const float* as2  = (const float*)d_in[14];
    const float* ad2  = (const float*)d_in[15];
    const float* b2   = (const float*)d_in[16];
    const float* g2   = (const float*)d_in[17];
    const float* be2  = (const float*)d_in[18];
    const float* lw2  = (const float*)d_in[19];
    const float* lb2  = (const float*)d_in[20];
    const float* gl2  = (const float*)d_in[21];
    const float* bel2 = (const float*)d_in[22];
    const float* W3   = (const float*)d_in[23];
    const float* as3  = (const float*)d_in[24];
    const float* ad3  = (const float*)d_in[25];
    const float* b3   = (const float*)d_in[26];
    const float* g3   = (const float*)d_in[27];
    const float* be3  = (const float*)d_in[28];
    const float* lwf  = (const float*)d_in[29];
    const float* lbf  = (const float*)d_in[30];
    float* out = (float*)d_out;

    // ---- workspace carve ----
    char* p = (char*)d_ws;
    auto alloc = [&](size_t bytes) {
        char* r = p;
        p += (bytes + 255) & ~(size_t)255;
        return r;
    };
    int*   rowptr = (int*)alloc(4 * (size_t)(N_NODES + 1));
    int*   cursor = (int*)alloc(4 * (size_t)N_NODES);
    int*   deg    = (int*)alloc(4 * (size_t)N_NODES);
    int*   col    = (int*)alloc(4 * (size_t)TOT_E);
    int*   cdst   = (int*)alloc(4 * (size_t)TOT_E);
    float* ssrc   = (float*)alloc(4 * (size_t)N_NODES * 20);
    float* sdst   = (float*)alloc(4 * (size_t)N_NODES * 20);
    float* ew     = (float*)alloc(4 * (size_t)TOT_E * 20);
    u16*   hbuf   = (u16*)alloc(2 * (size_t)N_NODES * 512);
    float* obuf   = (float*)alloc(4 * (size_t)N_NODES * 512);
    float* xbuf   = (float*)alloc(4 * (size_t)N_NODES * 32);
    float* psum   = (float*)alloc(4 * (size_t)PB * 512);
    float* psumsq = (float*)alloc(4 * (size_t)PB * 512);
    float* scA    = (float*)alloc(4 * 512);
    float* shA    = (float*)alloc(4 * 512);
    float* scB    = (float*)alloc(4 * 64);
    float* shB    = (float*)alloc(4 * 64);
    float* pooled = (float*)alloc(4 * (size_t)G_GRAPHS * 384);
    int*   cnt    = (int*)alloc(4 * G_GRAPHS);

    const int LB = (N_NODES + 63) / 64;  // 782 row-tiles for k_lin

    // ---- graph build (reused by all 3 layers) ----
    k_init_deg<<<(N_NODES + 255) / 256, 256, 0, stream>>>(deg);
    k_hist<<<(N_EDGES + 255) / 256, 256, 0, stream>>>(ei, deg);
    k_scan<<<1, 1024, 0, stream>>>(deg, rowptr, cursor);
    k_scatter<<<(TOT_E + 255) / 256, 256, 0, stream>>>(ei, cursor, col, cdst);
    hipMemsetAsync(pooled, 0, 4 * (size_t)G_GRAPHS * 384 + 256, stream);  // pooled + cnt

    // ---- layer 1: GAT(128 -> 20x16) ----
    k_gemm<128, 320, false><<<(N_NODES + 15) / 16, 320, 0, stream>>>(x, W1, nullptr, nullptr, hbuf);
    k_scores<20, 16><<<(N_NODES * 20 + 255) / 256, 256, 0, stream>>>(hbuf, as1, ad1, ssrc, sdst);
    k_ew<20><<<(TOT_E * 20 + 255) / 256, 256, 0, stream>>>(ssrc, sdst, col, cdst, ew);
    k_agg<20, 16><<<(N_NODES + 3) / 4, 256, 0, stream>>>(hbuf, ew, rowptr, col, b1, obuf);
    k_bnstats<320><<<PB, 320, 0, stream>>>(obuf, psum, psumsq);
    k_bnfinal<<<1, 512, 0, stream>>>(psum, psumsq, g1, be1, scA, shA, 320);
    k_lin<320, 16, 4><<<LB, 256, 0, stream>>>(obuf, lw1, lb1, scA, shA, xbuf);
    k_bnstats<16><<<PB, 256, 0, stream>>>(xbuf, psum, psumsq);
    k_bnfinal<<<1, 512, 0, stream>>>(psum, psumsq, gl1, bel1, scB, shB, 16);

    // ---- layer 2: GAT(16 -> 16x32) ----
    k_gemm<16, 512, true><<<(N_NODES + 15) / 16, 512, 0, stream>>>(xbuf, W2, scB, shB, hbuf);
    k_scores<16, 32><<<(N_NODES * 16 + 255) / 256, 256, 0, stream>>>(hbuf, as2, ad2, ssrc, sdst);
    k_ew<16><<<(TOT_E * 16 + 255) / 256, 256, 0, stream>>>(ssrc, sdst, col, cdst, ew);
    k_agg<16, 32><<<(N_NODES + 3) / 4, 256, 0, stream>>>(hbuf, ew, rowptr, col, b2, obuf);
    k_bnstats<512><<<PB, 512, 0, stream>>>(obuf, psum, psumsq);
    k_bnfinal<<<1, 512, 0, stream>>>(psum, psumsq, g2, be2, scA, shA, 512);
    k_lin<512, 32, 4><<<LB, 256, 0, stream>>>(obuf, lw2, lb2, scA, shA, xbuf);
    k_bnstats<32><<<PB, 256, 0, stream>>>(xbuf, psum, psumsq);
    k_bnfinal<<<1, 512, 0, stream>>>(psum, psumsq, gl2, bel2, scB, shB, 32);

    // ---- layer 3: GAT(32 -> 8x48) ----
    k_gemm<32, 384, true><<<(N_NODES + 15) / 16, 384, 0, stream>>>(xbuf, W3, scB, shB, hbuf);
    k_scores<8, 48><<<(N_NODES * 8 + 255) / 256, 256, 0, stream>>>(hbuf, as3, ad3, ssrc, sdst);
    k_ew<8><<<(TOT_E * 8 + 255) / 256, 256, 0, stream>>>(ssrc, sdst, col, cdst, ew);
    k_agg<8, 48><<<(N_NODES + 3) / 4, 256, 0, stream>>>(hbuf, ew, rowptr, col, b3, obuf);
    k_bnstats<384><<<PB, 384, 0, stream>>>(obuf, psum, psumsq);
    k_bnfinal<<<1, 512, 0, stream>>>(psum, psumsq, g3, be3, scA, shA, 384);

    // ---- pool + classifier ----
    k_bhist<<<(N_NODES + 255) / 256, 256, 0, stream>>>(batch, cnt);
    k_pool<<<512, 384, 0, stream>>>(obuf, batch, scA, shA, pooled);
    k_final<<<1, 640, 0, stream>>>(pooled, cnt, lwf, lbf, out);
}